// Round 8
// baseline (181.186 us; speedup 1.0000x reference)
//
#include <hip/hip_runtime.h>

// ---------- types ----------
typedef __attribute__((ext_vector_type(8)))  _Float16 half8;
typedef __attribute__((ext_vector_type(4)))  _Float16 half4;
typedef __attribute__((ext_vector_type(2)))  __fp16   fp16x2;
typedef __attribute__((ext_vector_type(4)))  float    f32x4;

#define MFMA16(a,b,c) __builtin_amdgcn_mfma_f32_16x16x32_f16(a,b,c,0,0,0)

// constants
#define QSCALE       0.17677669529663687f   // 32^-0.5
#define LAMBDA_INIT  0.3555090675909693f
#define OUT_SCALE    0.6444909324090307f    // 1 - LAMBDA_INIT
#define LOG2E        1.4426950408889634f
#define MSHIFT       4.0f                   // fixed softmax shift (log2 domain)

#define EXP2(x) __builtin_amdgcn_exp2f(x)   // bare v_exp_f32 (no ocml range bloat)

__device__ __forceinline__ void gld16(const void* g, void* l) {
    __builtin_amdgcn_global_load_lds(
        (const __attribute__((address_space(1))) unsigned int*)g,
        (__attribute__((address_space(3))) unsigned int*)l, 16, 0, 0);
}

// ---------- prep: fused cvt + transposes ----------
__device__ __forceinline__ void tr64(const float* __restrict__ src,
                                     _Float16* __restrict__ dst,
                                     int srcld, int dstld, int bx, int by) {
    __shared__ float t[64][65];
    int k0 = bx * 64, n0 = by * 64;
    int c = threadIdx.x & 63, rr = threadIdx.x >> 6;
#pragma unroll
    for (int ph = 0; ph < 16; ++ph) {
        int k = ph * 4 + rr;
        t[k][c] = src[(size_t)(k0 + k) * srcld + n0 + c];
    }
    __syncthreads();
#pragma unroll
    for (int ph = 0; ph < 16; ++ph) {
        int n = ph * 4 + rr;
        dst[(size_t)(n0 + n) * dstld + k0 + c] = (_Float16)t[c][n];
    }
}

__global__ __launch_bounds__(256) void k_prep(const float* __restrict__ x,
                                              const float* __restrict__ Wq,
                                              const float* __restrict__ Wkv,
                                              const float* __restrict__ Wout,
                                              _Float16* __restrict__ xh,
                                              _Float16* __restrict__ WallT,
                                              _Float16* __restrict__ WoutT) {
    int b = blockIdx.x;
    if (b < 4096) {
        int i = (b * 256 + threadIdx.x) * 4;
        f32x4 v = *(const f32x4*)(x + i);
        half4 h;
        h[0] = (_Float16)v[0]; h[1] = (_Float16)v[1];
        h[2] = (_Float16)v[2]; h[3] = (_Float16)v[3];
        *(half4*)(xh + i) = h;
    } else if (b < 4224) {
        int idx = b - 4096;                       // Wq: [1024][512] -> WallT rows 0..511
        tr64(Wq, WallT, 512, 1024, idx & 15, idx >> 4);
    } else if (b < 4480) {
        int idx = b - 4224;                       // Wkv: [1024][1024] -> WallT rows 512..1535
        tr64(Wkv, WallT + 512 * 1024, 1024, 1024, idx & 15, idx >> 4);
    } else {
        int idx = b - 4480;                       // Wout: [512][1024] -> WoutT [1024][512]
        tr64(Wout, WoutT, 1024, 512, idx & 7, idx >> 3);
    }
}

// ---------- shared GEMM main loop: C[128x128] = A[M][K] * Bt[N][K]^T ----------
__device__ __forceinline__ void gemm_loop(const _Float16* __restrict__ A,
                                          const _Float16* __restrict__ Bt,
                                          int K, int bm, int bn,
                                          char* As, char* Bs,
                                          f32x4 (&acc)[4][4]) {
    int tid = threadIdx.x, lane = tid & 63, w = tid >> 6;
    int col16 = lane & 15, quad = lane >> 4;
    int wm = (w >> 1) << 6, wn = (w & 1) << 6;
    int r0 = tid >> 2;
    int kc = (tid & 3) << 3;
    const _Float16* ga0 = A  + (size_t)(bm + r0) * K + kc;
    const _Float16* ga1 = A  + (size_t)(bm + 64 + r0) * K + kc;
    const _Float16* gb0 = Bt + (size_t)(bn + r0) * K + kc;
    const _Float16* gb1 = Bt + (size_t)(bn + 64 + r0) * K + kc;
    char* lA = As + (w << 10);
    char* lB = Bs + (w << 10);

    for (int k0 = 0; k0 < K; k0 += 32) {
        __syncthreads();
        gld16(ga0 + k0, lA);
        gld16(ga1 + k0, lA + 4096);
        gld16(gb0 + k0, lB);
        gld16(gb1 + k0, lB + 4096);
        __syncthreads();
        half8 af[4], bf[4];
#pragma unroll
        for (int i = 0; i < 4; ++i)
            af[i] = *(const half8*)(As + ((wm + i * 16 + col16) << 6) + (quad << 4));
#pragma unroll
        for (int j = 0; j < 4; ++j)
            bf[j] = *(const half8*)(Bs + ((wn + j * 16 + col16) << 6) + (quad << 4));
#pragma unroll
        for (int i = 0; i < 4; ++i)
#pragma unroll
            for (int j = 0; j < 4; ++j)
                acc[i][j] = MFMA16(af[i], bf[j], acc[i][j]);
    }
}

// ---------- GEMM1: x @ [Wq|Wk|Wv] -> q rows + K fragments + V fragments ----------
// Kf layout: per (b*8+p, kb32): 4KB = [frag(4)][lane(64)][16B]
// Vf layout: per (b*8+p, kb32): 4KB = [t(4)][lane(64)][16B], key permutation baked in
__global__ __launch_bounds__(256) void k_gemm_qkv(const _Float16* __restrict__ xh,
                                                  const _Float16* __restrict__ WallT,
                                                  _Float16* __restrict__ qbuf,
                                                  char* __restrict__ Kf,
                                                  char* __restrict__ Vf) {
    __shared__ __align__(16) char As[8192];
    __shared__ __align__(16) char Bs[8192];
    f32x4 acc[4][4] = {};
    int bm = blockIdx.x * 128, bn = blockIdx.y * 128;
    gemm_loop(xh, WallT, 1024, bm, bn, As, Bs, acc);

    int tid = threadIdx.x, lane = tid & 63, w = tid >> 6;
    int col16 = lane & 15, quad = lane >> 4;
    int wm = (w >> 1) << 6, wn = (w & 1) << 6;

    if (bn < 512) {  // q, pre-scaled into log2-softmax domain
        const float s = QSCALE * LOG2E;
#pragma unroll
        for (int i = 0; i < 4; ++i)
#pragma unroll
            for (int j = 0; j < 4; ++j) {
                int n = bn + wn + j * 16 + col16;
                int m0 = bm + wm + i * 16 + quad * 4;
#pragma unroll
                for (int r = 0; r < 4; ++r)
                    qbuf[(size_t)(m0 + r) * 512 + n] = (_Float16)(acc[i][j][r] * s);
            }
    } else if (bn < 1024) {  // K fragments
#pragma unroll
        for (int j = 0; j < 4; ++j) {
            int n = bn + wn + j * 16 + col16 - 512;
            int pp = n >> 6, dd = n & 63, head = dd >> 5, d32 = dd & 31;
            int lbase = (d32 >> 3) << 4;
            int e2 = (d32 & 7) << 1;
            int fragb = head << 11;
#pragma unroll
            for (int i = 0; i < 4; ++i) {
                int m0 = bm + wm + i * 16 + quad * 4;
                int b = m0 >> 11, tok = m0 & 2047, kb = tok >> 5, kk = tok & 31;
                char* dst = Kf + (((size_t)((b * 8 + pp) * 64 + kb)) << 12)
                          + fragb + ((kk >> 4) << 10) + ((lbase + (kk & 15)) << 4) + e2;
#pragma unroll
                for (int r = 0; r < 4; ++r)
                    *(_Float16*)(dst + (r << 4)) = (_Float16)acc[i][j][r];
            }
        }
    } else {  // V fragments (key permutation kappa baked in)
#pragma unroll
        for (int j = 0; j < 4; ++j) {
            int n = bn + wn + j * 16 + col16 - 1024;
            int pp = n >> 6, ch = n & 63;
            int off_t = ((ch >> 4) << 10) + ((ch & 15) << 4);
#pragma unroll
            for (int i = 0; i < 4; ++i) {
                int m0 = bm + wm + i * 16 + quad * 4;
                int b = m0 >> 11, tok = m0 & 2047, kb = tok >> 5, kk = tok & 31;
                int quadv = (kk < 16) ? (kk >> 2) : ((kk - 16) >> 2);
                int e0 = (kk < 16) ? 0 : 4;
                half4 hv;
#pragma unroll
                for (int r = 0; r < 4; ++r) hv[r] = (_Float16)acc[i][j][r];
                *(half4*)(Vf + (((size_t)((b * 8 + pp) * 64 + kb)) << 12)
                          + off_t + (quadv << 8) + (e0 << 1)) = hv;
            }
        }
    }
}

// ---------- single-pass fixed-shift flash differential attention (split-K) ----------
// grid nc*512; block 256 = 4 waves x 16 q-rows. NO LDS: K/V fragments loaded
// straight from global (fragment-ordered layout, coalesced dwordx4; per-iter
// working set 8KB/block is L1-resident so the 4-wave redundancy hits L1).
// No barriers in the K-loop -> waves free-run, pipes overlap.
template <int ITERS>
__global__ __launch_bounds__(256) void k_attn(const _Float16* __restrict__ qbuf,
                                              const char* __restrict__ Kf,
                                              const char* __restrict__ Vf,
                                              _Float16* __restrict__ Po,
                                              float* __restrict__ Pl) {
    int blk = blockIdx.x;
    int qt = blk & 31, p = (blk >> 5) & 7, bb = (blk >> 8) & 1, c = blk >> 9;
    int tid = threadIdx.x, lane = tid & 63, w = tid >> 6;
    int col16 = lane & 15, quad = lane >> 4;

    int qrow = bb * 2048 + qt * 64 + w * 16 + col16;
    const _Float16* qb = qbuf + (size_t)qrow * 512 + p * 64;
    half8 q1 = *(const half8*)(qb + quad * 8);
    half8 q2 = *(const half8*)(qb + 32 + quad * 8);

    size_t choff = (size_t)c * ((size_t)ITERS << 13);
    const char* Kb = Kf + (((size_t)(bb * 8 + p)) << 18) + choff + (lane << 4);
    const char* Vb = Vf + (((size_t)(bb * 8 + p)) << 18) + choff + (lane << 4);
    const f32x4 minit = {-MSHIFT, -MSHIFT, -MSHIFT, -MSHIFT};  // QK acc starts at -shift

    float l1 = 0.f, l2 = 0.f;
    f32x4 o1[4] = {}, o2[4] = {};

    for (int it = 0; it < ITERS; ++it) {
        const char* kb = Kb + ((size_t)it << 13);
        const char* vb = Vb + ((size_t)it << 13);
#pragma unroll
        for (int g = 0; g < 2; ++g) {
            const char* kbase = kb + (g << 12);
            const char* vbase = vb + (g << 12);
            half8 kf0 = *(const half8*)(kbase);
            half8 kf1 = *(const half8*)(kbase + 1024);
            half8 kf2 = *(const half8*)(kbase + 2048);
            half8 kf3 = *(const half8*)(kbase + 3072);
            half8 vf0 = *(const half8*)(vbase);
            half8 vf1 = *(const half8*)(vbase + 1024);
            half8 vf2 = *(const half8*)(vbase + 2048);
            half8 vf3 = *(const half8*)(vbase + 3072);
            f32x4 sa1 = MFMA16(kf0, q1, minit), sb1 = MFMA16(kf1, q1, minit);
            f32x4 sa2 = MFMA16(kf2, q2, minit), sb2 = MFMA16(kf3, q2, minit);

            union { half8 v; fp16x2 h[4]; } p1u, p2u;
            {
                float a0 = EXP2(sa1[0]), a1 = EXP2(sa1[1]);
                float a2 = EXP2(sa1[2]), a3 = EXP2(sa1[3]);
                float b0 = EXP2(sb1[0]), b1 = EXP2(sb1[1]);
                float b2 = EXP2(sb1[2]), b3 = EXP2(sb1[3]);
                l1 += ((a0 + a1) + (a2 + a3)) + ((b0 + b1) + (b2 + b3));
                p1u.h[0] = __builtin_amdgcn_cvt_pkrtz(a0, a1);
                p1u.h[1] = __builtin_amdgcn_cvt_pkrtz(a2, a3);
                p1u.h[2] = __builtin_amdgcn_cvt_pkrtz(b0, b1);
                p1u.h[3] = __builtin_amdgcn_cvt_pkrtz(b2, b3);
            }
            {
                float a0 = EXP2(sa2[0]), a1 = EXP2(sa2[1]);
                float a2 = EXP2(sa2[2]), a3 = EXP2(sa2[3]);
                float b0 = EXP2(sb2[0]), b1 = EXP2(sb2[1]);
                float b2 = EXP2(sb2[2]), b3 = EXP2(sb2[3]);
                l2 += ((a0 + a1) + (a2 + a3)) + ((b0 + b1) + (b2 + b3));
                p2u.h[0] = __builtin_amdgcn_cvt_pkrtz(a0, a1);
                p2u.h[1] = __builtin_amdgcn_cvt_pkrtz(a2, a3);
                p2u.h[2] = __builtin_amdgcn_cvt_pkrtz(b0, b1);
                p2u.h[3] = __builtin_amdgcn_cvt_pkrtz(b2, b3);
            }
            o1[0] = MFMA16(p1u.v, vf0, o1[0]); o2[0] = MFMA16(p2u.v, vf0, o2[0]);
            o1[1] = MFMA16(p1u.v, vf1, o1[1]); o2[1] = MFMA16(p2u.v, vf1, o2[1]);
            o1[2] = MFMA16(p1u.v, vf2, o1[2]); o2[2] = MFMA16(p2u.v, vf2, o2[2]);
            o1[3] = MFMA16(p1u.v, vf3, o1[3]); o2[3] = MFMA16(p2u.v, vf3, o2[3]);
        }
    }
    l1 += __shfl_xor(l1, 16); l1 += __shfl_xor(l1, 32);
    l2 += __shfl_xor(l2, 16); l2 += __shfl_xor(l2, 32);

    // ---- store partials ----
    int rowbase = (bb * 8 + p) * 2048 + qt * 64 + w * 16;
    _Float16* PoC = Po + (size_t)c * 4194304 + (size_t)rowbase * 128;
#pragma unroll
    for (int r = 0; r < 4; ++r) {
        int rl = quad * 4 + r;
        _Float16* dst = PoC + (size_t)rl * 128 + col16;
#pragma unroll
        for (int t = 0; t < 4; ++t) {
            dst[t * 16]      = (_Float16)o1[t][r];
            dst[64 + t * 16] = (_Float16)o2[t][r];
        }
    }
    if (quad == 0) {
        int idx = rowbase + col16;
        Pl[c * 65536 + idx]         = l1;
        Pl[c * 65536 + 32768 + idx] = l2;
    }
}

// ---------- combine: sum chunks, diff, RMS norm, gamma -> f16 attn ----------
// grid 2048 x 256; 16 lanes per row-instance
__global__ __launch_bounds__(256) void k_combine(const _Float16* __restrict__ Po,
                                                 const float* __restrict__ Pl,
                                                 const float* __restrict__ lq1,
                                                 const float* __restrict__ lk1,
                                                 const float* __restrict__ lq2,
                                                 const float* __restrict__ lk2,
                                                 const float* __restrict__ gamma,
                                                 _Float16* __restrict__ attnO,
                                                 int nc) {
    int gid = blockIdx.x * 256 + threadIdx.x;
    int idx = gid >> 4, j = gid & 15;

    float s1 = 0.f, s2 = 0.f;
#pragma unroll
    for (int i = 0; i < 32; ++i) { s1 += lq1[i] * lk1[i]; s2 += lq2[i] * lk2[i]; }
    float lam = __expf(s1) - __expf(s2) + LAMBDA_INIT;

    size_t rb = (size_t)idx * 128 + j * 4;
    float l1 = 0.f, l2 = 0.f;
    float o1[4] = {}, o2[4] = {};
    for (int c = 0; c < nc; ++c) {
        half4 c1 = *(const half4*)(Po + (size_t)c * 4194304 + rb);
        half4 c2 = *(const half4*)(Po + (size_t)c * 4194304 + rb + 64);
        l1 += Pl[c * 65536 + idx];
        l2 += Pl[c * 65536 + 32768 + idx];
#pragma unroll
        for (int e = 0; e < 4; ++e) { o1[e] += (float)c1[e]; o2[e] += (float)c2[e]; }
    }
    float il1 = 1.f / l1, il2 = lam / l2;
    float Of[4], ss = 0.f;
#pragma unroll
    for (int e = 0; e < 4; ++e) {
        Of[e] = o1[e] * il1 - o2[e] * il2;
        ss += Of[e] * Of[e];
    }
    ss += __shfl_xor(ss, 1, 16); ss += __shfl_xor(ss, 2, 16);
    ss += __shfl_xor(ss, 4, 16); ss += __shfl_xor(ss, 8, 16);
    float rms = sqrtf(ss * 0.015625f);
    float sc = OUT_SCALE / (rms + 1e-8f);

    int b = idx >> 14, p = (idx >> 11) & 7, t = idx & 2047;
    half4 o;
#pragma unroll
    for (int e = 0; e < 4; ++e) o[e] = (_Float16)(gamma[j * 4 + e] * Of[e] * sc);
    *(half4*)(attnO + ((size_t)(b * 2048 + t) * 512) + p * 64 + j * 4) = o;
}

// ---------- GEMM2: attn @ Wout -> fp32 out ----------
__global__ __launch_bounds__(256) void k_gemm_out(const _Float16* __restrict__ attn,
                                                  const _Float16* __restrict__ WoutT,
                                                  float* __restrict__ out) {
    __shared__ __align__(16) char As[8192];
    __shared__ __align__(16) char Bs[8192];
    f32x4 acc[4][4] = {};
    int bm = blockIdx.x * 128, bn = blockIdx.y * 128;
    gemm_loop(attn, WoutT, 512, bm, bn, As, Bs, acc);

    int tid = threadIdx.x, lane = tid & 63, w = tid >> 6;
    int col16 = lane & 15, quad = lane >> 4;
    int wm = (w >> 1) << 6, wn = (w & 1) << 6;
#pragma unroll
    for (int i = 0; i < 4; ++i)
#pragma unroll
        for (int j = 0; j < 4; ++j) {
            int n = bn + wn + j * 16 + col16;
            int m0 = bm + wm + i * 16 + quad * 4;
#pragma unroll
            for (int r = 0; r < 4; ++r)
                out[(size_t)(m0 + r) * 1024 + n] = acc[i][j][r];
        }
}

// ---------- launch ----------
extern "C" void kernel_launch(void* const* d_in, const int* in_sizes, int n_in,
                              void* d_out, int out_size, void* d_ws, size_t ws_size,
                              hipStream_t stream) {
    const float* x     = (const float*)d_in[0];
    const float* Wq    = (const float*)d_in[1];
    const float* Wkv   = (const float*)d_in[2];
    const float* Wout  = (const float*)d_in[3];
    const float* lq1   = (const float*)d_in[4];
    const float* lk1   = (const float*)d_in[5];
    const float* lq2   = (const float*)d_in[6];
    const float* lk2   = (const float*)d_in[7];
    const float* gamma = (const float*)d_in[8];
    float* out = (float*)d_out;

    char* ws = (char*)d_ws;
    // Layout: [xh 8M][WallT 3M | Pl 1M overlay][WoutT 1M][qbuf 4M][Kf 4M][Vf 4M]
    //         [attn 4M][Po nc*8M @28M]. Peak (nc=2): 44 MB; ws measured 256 MiB.
    _Float16* xh    = (_Float16*)(ws);                 // 4096*1024  (8 MB)
    _Float16* WallT = (_Float16*)(ws + 8388608);       // 1536*1024  (3 MB)
    float*    Pl    = (float*)(ws + 8388608);          // nc*2*32768 (<=512 KB, overlays WallT)
    _Float16* WoutT = (_Float16*)(ws + 11534336);      // 1024*512   (1 MB)
    _Float16* qbuf  = (_Float16*)(ws + 12582912);      // 4096*512   (4 MB)
    char*     Kf    = (char*)(ws + 16777216);          // 16*64*4096 (4 MB)
    char*     Vf    = (char*)(ws + 20971520);          // 16*64*4096 (4 MB)
    _Float16* attn  = (_Float16*)(ws + 25165824);      // 4096*512   (4 MB)
    _Float16* Po    = (_Float16*)(ws + 29360128);      // nc*4194304 elems (nc*8 MB)

    int nc = (ws_size >= 46137344u) ? 2 : 1;           // fall back if ws too small

    k_prep<<<4608, 256, 0, stream>>>(x, Wq, Wkv, Wout, xh, WallT, WoutT);
    k_gemm_qkv<<<dim3(32, 12), 256, 0, stream>>>(xh, WallT, qbuf, Kf, Vf);
    if (nc == 2)
        k_attn<16><<<1024, 256, 0, stream>>>(qbuf, Kf, Vf, Po, Pl);
    else
        k_attn<32><<<512, 256, 0, stream>>>(qbuf, Kf, Vf, Po, Pl);
    k_combine<<<2048, 256, 0, stream>>>(Po, Pl, lq1, lk1, lq2, lk2, gamma, attn, nc);
    k_gemm_out<<<dim3(32, 8), 256, 0, stream>>>(attn, WoutT, out);
}

// Round 10
// 177.756 us; speedup vs baseline: 1.0193x; 1.0193x over previous
//
#include <hip/hip_runtime.h>

// ---------- types ----------
typedef __attribute__((ext_vector_type(8)))  _Float16 half8;
typedef __attribute__((ext_vector_type(4)))  _Float16 half4;
typedef __attribute__((ext_vector_type(2)))  __fp16   fp16x2;
typedef __attribute__((ext_vector_type(4)))  float    f32x4;

#define MFMA16(a,b,c) __builtin_amdgcn_mfma_f32_16x16x32_f16(a,b,c,0,0,0)

// constants
#define QSCALE       0.17677669529663687f   // 32^-0.5
#define LAMBDA_INIT  0.3555090675909693f
#define OUT_SCALE    0.6444909324090307f    // 1 - LAMBDA_INIT
#define LOG2E        1.4426950408889634f
#define MSHIFT       4.0f                   // fixed softmax shift (log2 domain)

#define EXP2(x) __builtin_amdgcn_exp2f(x)   // bare v_exp_f32 (no ocml range bloat)

__device__ __forceinline__ void gld16(const void* g, void* l) {
    __builtin_amdgcn_global_load_lds(
        (const __attribute__((address_space(1))) unsigned int*)g,
        (__attribute__((address_space(3))) unsigned int*)l, 16, 0, 0);
}

// ---------- prep: fused cvt + transposes ----------
__device__ __forceinline__ void tr64(const float* __restrict__ src,
                                     _Float16* __restrict__ dst,
                                     int srcld, int dstld, int bx, int by) {
    __shared__ float t[64][65];
    int k0 = bx * 64, n0 = by * 64;
    int c = threadIdx.x & 63, rr = threadIdx.x >> 6;
#pragma unroll
    for (int ph = 0; ph < 16; ++ph) {
        int k = ph * 4 + rr;
        t[k][c] = src[(size_t)(k0 + k) * srcld + n0 + c];
    }
    __syncthreads();
#pragma unroll
    for (int ph = 0; ph < 16; ++ph) {
        int n = ph * 4 + rr;
        dst[(size_t)(n0 + n) * dstld + k0 + c] = (_Float16)t[c][n];
    }
}

__global__ __launch_bounds__(256) void k_prep(const float* __restrict__ x,
                                              const float* __restrict__ Wq,
                                              const float* __restrict__ Wkv,
                                              const float* __restrict__ Wout,
                                              _Float16* __restrict__ xh,
                                              _Float16* __restrict__ WallT,
                                              _Float16* __restrict__ WoutT) {
    int b = blockIdx.x;
    if (b < 4096) {
        int i = (b * 256 + threadIdx.x) * 4;
        f32x4 v = *(const f32x4*)(x + i);
        half4 h;
        h[0] = (_Float16)v[0]; h[1] = (_Float16)v[1];
        h[2] = (_Float16)v[2]; h[3] = (_Float16)v[3];
        *(half4*)(xh + i) = h;
    } else if (b < 4224) {
        int idx = b - 4096;                       // Wq: [1024][512] -> WallT rows 0..511
        tr64(Wq, WallT, 512, 1024, idx & 15, idx >> 4);
    } else if (b < 4480) {
        int idx = b - 4224;                       // Wkv: [1024][1024] -> WallT rows 512..1535
        tr64(Wkv, WallT + 512 * 1024, 1024, 1024, idx & 15, idx >> 4);
    } else {
        int idx = b - 4480;                       // Wout: [512][1024] -> WoutT [1024][512]
        tr64(Wout, WoutT, 1024, 512, idx & 7, idx >> 3);
    }
}

// ---------- shared GEMM main loop: C[128x128] = A[M][K] * Bt[N][K]^T ----------
__device__ __forceinline__ void gemm_loop(const _Float16* __restrict__ A,
                                          const _Float16* __restrict__ Bt,
                                          int K, int bm, int bn,
                                          char* As, char* Bs,
                                          f32x4 (&acc)[4][4]) {
    int tid = threadIdx.x, lane = tid & 63, w = tid >> 6;
    int col16 = lane & 15, quad = lane >> 4;
    int wm = (w >> 1) << 6, wn = (w & 1) << 6;
    int r0 = tid >> 2;
    int kc = (tid & 3) << 3;
    const _Float16* ga0 = A  + (size_t)(bm + r0) * K + kc;
    const _Float16* ga1 = A  + (size_t)(bm + 64 + r0) * K + kc;
    const _Float16* gb0 = Bt + (size_t)(bn + r0) * K + kc;
    const _Float16* gb1 = Bt + (size_t)(bn + 64 + r0) * K + kc;
    char* lA = As + (w << 10);
    char* lB = Bs + (w << 10);

    for (int k0 = 0; k0 < K; k0 += 32) {
        __syncthreads();
        gld16(ga0 + k0, lA);
        gld16(ga1 + k0, lA + 4096);
        gld16(gb0 + k0, lB);
        gld16(gb1 + k0, lB + 4096);
        __syncthreads();
        half8 af[4], bf[4];
#pragma unroll
        for (int i = 0; i < 4; ++i)
            af[i] = *(const half8*)(As + ((wm + i * 16 + col16) << 6) + (quad << 4));
#pragma unroll
        for (int j = 0; j < 4; ++j)
            bf[j] = *(const half8*)(Bs + ((wn + j * 16 + col16) << 6) + (quad << 4));
#pragma unroll
        for (int i = 0; i < 4; ++i)
#pragma unroll
            for (int j = 0; j < 4; ++j)
                acc[i][j] = MFMA16(af[i], bf[j], acc[i][j]);
    }
}

// ---------- GEMM1: x @ [Wq|Wk|Wv] -> q rows + K fragments + V fragments ----------
// Kf layout: per (b*8+p, kb32): 4KB = [frag(4)][lane(64)][16B]
// Vf layout: per (b*8+p, kb32): 4KB = [t(4)][lane(64)][16B], key permutation baked in
__global__ __launch_bounds__(256) void k_gemm_qkv(const _Float16* __restrict__ xh,
                                                  const _Float16* __restrict__ WallT,
                                                  _Float16* __restrict__ qbuf,
                                                  char* __restrict__ Kf,
                                                  char* __restrict__ Vf) {
    __shared__ __align__(16) char As[8192];
    __shared__ __align__(16) char Bs[8192];
    f32x4 acc[4][4] = {};
    int bm = blockIdx.x * 128, bn = blockIdx.y * 128;
    gemm_loop(xh, WallT, 1024, bm, bn, As, Bs, acc);

    int tid = threadIdx.x, lane = tid & 63, w = tid >> 6;
    int col16 = lane & 15, quad = lane >> 4;
    int wm = (w >> 1) << 6, wn = (w & 1) << 6;

    if (bn < 512) {  // q, pre-scaled into log2-softmax domain
        const float s = QSCALE * LOG2E;
#pragma unroll
        for (int i = 0; i < 4; ++i)
#pragma unroll
            for (int j = 0; j < 4; ++j) {
                int n = bn + wn + j * 16 + col16;
                int m0 = bm + wm + i * 16 + quad * 4;
#pragma unroll
                for (int r = 0; r < 4; ++r)
                    qbuf[(size_t)(m0 + r) * 512 + n] = (_Float16)(acc[i][j][r] * s);
            }
    } else if (bn < 1024) {  // K fragments
#pragma unroll
        for (int j = 0; j < 4; ++j) {
            int n = bn + wn + j * 16 + col16 - 512;
            int pp = n >> 6, dd = n & 63, head = dd >> 5, d32 = dd & 31;
            int lbase = (d32 >> 3) << 4;
            int e2 = (d32 & 7) << 1;
            int fragb = head << 11;
#pragma unroll
            for (int i = 0; i < 4; ++i) {
                int m0 = bm + wm + i * 16 + quad * 4;
                int b = m0 >> 11, tok = m0 & 2047, kb = tok >> 5, kk = tok & 31;
                char* dst = Kf + (((size_t)((b * 8 + pp) * 64 + kb)) << 12)
                          + fragb + ((kk >> 4) << 10) + ((lbase + (kk & 15)) << 4) + e2;
#pragma unroll
                for (int r = 0; r < 4; ++r)
                    *(_Float16*)(dst + (r << 4)) = (_Float16)acc[i][j][r];
            }
        }
    } else {  // V fragments (key permutation kappa baked in)
#pragma unroll
        for (int j = 0; j < 4; ++j) {
            int n = bn + wn + j * 16 + col16 - 1024;
            int pp = n >> 6, ch = n & 63;
            int off_t = ((ch >> 4) << 10) + ((ch & 15) << 4);
#pragma unroll
            for (int i = 0; i < 4; ++i) {
                int m0 = bm + wm + i * 16 + quad * 4;
                int b = m0 >> 11, tok = m0 & 2047, kb = tok >> 5, kk = tok & 31;
                int quadv = (kk < 16) ? (kk >> 2) : ((kk - 16) >> 2);
                int e0 = (kk < 16) ? 0 : 4;
                half4 hv;
#pragma unroll
                for (int r = 0; r < 4; ++r) hv[r] = (_Float16)acc[i][j][r];
                *(half4*)(Vf + (((size_t)((b * 8 + pp) * 64 + kb)) << 12)
                          + off_t + (quadv << 8) + (e0 << 1)) = hv;
            }
        }
    }
}

// ---------- single-pass fixed-shift flash differential attention (split-K) ----------
// grid nc*512; block 256 = 4 waves x 16 q-rows. Single 16KB buffer, 2-barrier
// stage-then-read per 64-key iteration (exact gemm_loop staging idiom — proven).
// 16KB LDS -> 4 blocks/CU resident (16 waves/CU), vs 28% occupancy at 32KB dbuf.
template <int ITERS>
__global__ __launch_bounds__(256) void k_attn(const _Float16* __restrict__ qbuf,
                                              const char* __restrict__ Kf,
                                              const char* __restrict__ Vf,
                                              _Float16* __restrict__ Po,
                                              float* __restrict__ Pl) {
    __shared__ __align__(16) char Sh[16384];   // K 8KB + V 8KB

    int blk = blockIdx.x;
    int qt = blk & 31, p = (blk >> 5) & 7, bb = (blk >> 8) & 1, c = blk >> 9;
    int tid = threadIdx.x, lane = tid & 63, w = tid >> 6;
    int col16 = lane & 15, quad = lane >> 4;

    int qrow = bb * 2048 + qt * 64 + w * 16 + col16;
    const _Float16* qb = qbuf + (size_t)qrow * 512 + p * 64;
    half8 q1 = *(const half8*)(qb + quad * 8);
    half8 q2 = *(const half8*)(qb + 32 + quad * 8);

    size_t choff = (size_t)c * ((size_t)ITERS << 13);
    const char* Kb = Kf + (((size_t)(bb * 8 + p)) << 18) + choff;
    const char* Vb = Vf + (((size_t)(bb * 8 + p)) << 18) + choff;
    const f32x4 minit = {-MSHIFT, -MSHIFT, -MSHIFT, -MSHIFT};  // QK acc starts at -shift
    int t16 = tid << 4;

    float l1 = 0.f, l2 = 0.f;
    f32x4 o1[4] = {}, o2[4] = {};

    for (int it = 0; it < ITERS; ++it) {
        __syncthreads();
        const char* sk = Kb + ((size_t)it << 13);
        const char* sv = Vb + ((size_t)it << 13);
        gld16(sk + t16, Sh + t16);
        gld16(sk + 4096 + t16, Sh + 4096 + t16);
        gld16(sv + t16, Sh + 8192 + t16);
        gld16(sv + 4096 + t16, Sh + 12288 + t16);
        __syncthreads();
#pragma unroll
        for (int g = 0; g < 2; ++g) {
            const char* kbase = Sh + (g << 12) + (lane << 4);
            const char* vbase = Sh + 8192 + (g << 12) + (lane << 4);
            half8 kf0 = *(const half8*)(kbase);
            half8 kf1 = *(const half8*)(kbase + 1024);
            half8 kf2 = *(const half8*)(kbase + 2048);
            half8 kf3 = *(const half8*)(kbase + 3072);
            f32x4 sa1 = MFMA16(kf0, q1, minit), sb1 = MFMA16(kf1, q1, minit);
            f32x4 sa2 = MFMA16(kf2, q2, minit), sb2 = MFMA16(kf3, q2, minit);

            union { half8 v; fp16x2 h[4]; } p1u, p2u;
            {
                float a0 = EXP2(sa1[0]), a1 = EXP2(sa1[1]);
                float a2 = EXP2(sa1[2]), a3 = EXP2(sa1[3]);
                float b0 = EXP2(sb1[0]), b1 = EXP2(sb1[1]);
                float b2 = EXP2(sb1[2]), b3 = EXP2(sb1[3]);
                l1 += ((a0 + a1) + (a2 + a3)) + ((b0 + b1) + (b2 + b3));
                p1u.h[0] = __builtin_amdgcn_cvt_pkrtz(a0, a1);
                p1u.h[1] = __builtin_amdgcn_cvt_pkrtz(a2, a3);
                p1u.h[2] = __builtin_amdgcn_cvt_pkrtz(b0, b1);
                p1u.h[3] = __builtin_amdgcn_cvt_pkrtz(b2, b3);
            }
            {
                float a0 = EXP2(sa2[0]), a1 = EXP2(sa2[1]);
                float a2 = EXP2(sa2[2]), a3 = EXP2(sa2[3]);
                float b0 = EXP2(sb2[0]), b1 = EXP2(sb2[1]);
                float b2 = EXP2(sb2[2]), b3 = EXP2(sb2[3]);
                l2 += ((a0 + a1) + (a2 + a3)) + ((b0 + b1) + (b2 + b3));
                p2u.h[0] = __builtin_amdgcn_cvt_pkrtz(a0, a1);
                p2u.h[1] = __builtin_amdgcn_cvt_pkrtz(a2, a3);
                p2u.h[2] = __builtin_amdgcn_cvt_pkrtz(b0, b1);
                p2u.h[3] = __builtin_amdgcn_cvt_pkrtz(b2, b3);
            }
            half8 vf0 = *(const half8*)(vbase);
            half8 vf1 = *(const half8*)(vbase + 1024);
            half8 vf2 = *(const half8*)(vbase + 2048);
            half8 vf3 = *(const half8*)(vbase + 3072);
            o1[0] = MFMA16(p1u.v, vf0, o1[0]); o2[0] = MFMA16(p2u.v, vf0, o2[0]);
            o1[1] = MFMA16(p1u.v, vf1, o1[1]); o2[1] = MFMA16(p2u.v, vf1, o2[1]);
            o1[2] = MFMA16(p1u.v, vf2, o1[2]); o2[2] = MFMA16(p2u.v, vf2, o2[2]);
            o1[3] = MFMA16(p1u.v, vf3, o1[3]); o2[3] = MFMA16(p2u.v, vf3, o2[3]);
        }
    }
    l1 += __shfl_xor(l1, 16); l1 += __shfl_xor(l1, 32);
    l2 += __shfl_xor(l2, 16); l2 += __shfl_xor(l2, 32);

    // ---- store partials ----
    int rowbase = (bb * 8 + p) * 2048 + qt * 64 + w * 16;
    _Float16* PoC = Po + (size_t)c * 4194304 + (size_t)rowbase * 128;
#pragma unroll
    for (int r = 0; r < 4; ++r) {
        int rl = quad * 4 + r;
        _Float16* dst = PoC + (size_t)rl * 128 + col16;
#pragma unroll
        for (int t = 0; t < 4; ++t) {
            dst[t * 16]      = (_Float16)o1[t][r];
            dst[64 + t * 16] = (_Float16)o2[t][r];
        }
    }
    if (quad == 0) {
        int idx = rowbase + col16;
        Pl[c * 65536 + idx]         = l1;
        Pl[c * 65536 + 32768 + idx] = l2;
    }
}

// ---------- combine: sum chunks, diff, RMS norm, gamma -> f16 attn ----------
// grid 2048 x 256; 16 lanes per row-instance
__global__ __launch_bounds__(256) void k_combine(const _Float16* __restrict__ Po,
                                                 const float* __restrict__ Pl,
                                                 const float* __restrict__ lq1,
                                                 const float* __restrict__ lk1,
                                                 const float* __restrict__ lq2,
                                                 const float* __restrict__ lk2,
                                                 const float* __restrict__ gamma,
                                                 _Float16* __restrict__ attnO,
                                                 int nc) {
    int gid = blockIdx.x * 256 + threadIdx.x;
    int idx = gid >> 4, j = gid & 15;

    float s1 = 0.f, s2 = 0.f;
#pragma unroll
    for (int i = 0; i < 32; ++i) { s1 += lq1[i] * lk1[i]; s2 += lq2[i] * lk2[i]; }
    float lam = __expf(s1) - __expf(s2) + LAMBDA_INIT;

    size_t rb = (size_t)idx * 128 + j * 4;
    float l1 = 0.f, l2 = 0.f;
    float o1[4] = {}, o2[4] = {};
    for (int c = 0; c < nc; ++c) {
        half4 c1 = *(const half4*)(Po + (size_t)c * 4194304 + rb);
        half4 c2 = *(const half4*)(Po + (size_t)c * 4194304 + rb + 64);
        l1 += Pl[c * 65536 + idx];
        l2 += Pl[c * 65536 + 32768 + idx];
#pragma unroll
        for (int e = 0; e < 4; ++e) { o1[e] += (float)c1[e]; o2[e] += (float)c2[e]; }
    }
    float il1 = 1.f / l1, il2 = lam / l2;
    float Of[4], ss = 0.f;
#pragma unroll
    for (int e = 0; e < 4; ++e) {
        Of[e] = o1[e] * il1 - o2[e] * il2;
        ss += Of[e] * Of[e];
    }
    ss += __shfl_xor(ss, 1, 16); ss += __shfl_xor(ss, 2, 16);
    ss += __shfl_xor(ss, 4, 16); ss += __shfl_xor(ss, 8, 16);
    float rms = sqrtf(ss * 0.015625f);
    float sc = OUT_SCALE / (rms + 1e-8f);

    int b = idx >> 14, p = (idx >> 11) & 7, t = idx & 2047;
    half4 o;
#pragma unroll
    for (int e = 0; e < 4; ++e) o[e] = (_Float16)(gamma[j * 4 + e] * Of[e] * sc);
    *(half4*)(attnO + ((size_t)(b * 2048 + t) * 512) + p * 64 + j * 4) = o;
}

// ---------- GEMM2: attn @ Wout -> fp32 out ----------
__global__ __launch_bounds__(256) void k_gemm_out(const _Float16* __restrict__ attn,
                                                  const _Float16* __restrict__ WoutT,
                                                  float* __restrict__ out) {
    __shared__ __align__(16) char As[8192];
    __shared__ __align__(16) char Bs[8192];
    f32x4 acc[4][4] = {};
    int bm = blockIdx.x * 128, bn = blockIdx.y * 128;
    gemm_loop(attn, WoutT, 512, bm, bn, As, Bs, acc);

    int tid = threadIdx.x, lane = tid & 63, w = tid >> 6;
    int col16 = lane & 15, quad = lane >> 4;
    int wm = (w >> 1) << 6, wn = (w & 1) << 6;
#pragma unroll
    for (int i = 0; i < 4; ++i)
#pragma unroll
        for (int j = 0; j < 4; ++j) {
            int n = bn + wn + j * 16 + col16;
            int m0 = bm + wm + i * 16 + quad * 4;
#pragma unroll
            for (int r = 0; r < 4; ++r)
                out[(size_t)(m0 + r) * 1024 + n] = acc[i][j][r];
        }
}

// ---------- launch ----------
extern "C" void kernel_launch(void* const* d_in, const int* in_sizes, int n_in,
                              void* d_out, int out_size, void* d_ws, size_t ws_size,
                              hipStream_t stream) {
    const float* x     = (const float*)d_in[0];
    const float* Wq    = (const float*)d_in[1];
    const float* Wkv   = (const float*)d_in[2];
    const float* Wout  = (const float*)d_in[3];
    const float* lq1   = (const float*)d_in[4];
    const float* lk1   = (const float*)d_in[5];
    const float* lq2   = (const float*)d_in[6];
    const float* lk2   = (const float*)d_in[7];
    const float* gamma = (const float*)d_in[8];
    float* out = (float*)d_out;

    char* ws = (char*)d_ws;
    // Layout: [xh 8M][WallT 3M | Pl 1M overlay][WoutT 1M][qbuf 4M][Kf 4M][Vf 4M]
    //         [attn 4M][Po nc*8M @28M]. Peak (nc=2): 44 MB; ws measured 256 MiB.
    _Float16* xh    = (_Float16*)(ws);                 // 4096*1024  (8 MB)
    _Float16* WallT = (_Float16*)(ws + 8388608);       // 1536*1024  (3 MB)
    float*    Pl    = (float*)(ws + 8388608);          // nc*2*32768 (<=512 KB, overlays WallT)
    _Float16* WoutT = (_Float16*)(ws + 11534336);      // 1024*512   (1 MB)
    _Float16* qbuf  = (_Float16*)(ws + 12582912);      // 4096*512   (4 MB)
    char*     Kf    = (char*)(ws + 16777216);          // 16*64*4096 (4 MB)
    char*     Vf    = (char*)(ws + 20971520);          // 16*64*4096 (4 MB)
    _Float16* attn  = (_Float16*)(ws + 25165824);      // 4096*512   (4 MB)
    _Float16* Po    = (_Float16*)(ws + 29360128);      // nc*4194304 elems (nc*8 MB)

    int nc = (ws_size >= 46137344u) ? 2 : 1;           // fall back if ws too small

    k_prep<<<4608, 256, 0, stream>>>(x, Wq, Wkv, Wout, xh, WallT, WoutT);
    k_gemm_qkv<<<dim3(32, 12), 256, 0, stream>>>(xh, WallT, qbuf, Kf, Vf);
    if (nc == 2)
        k_attn<16><<<1024, 256, 0, stream>>>(qbuf, Kf, Vf, Po, Pl);
    else
        k_attn<32><<<512, 256, 0, stream>>>(qbuf, Kf, Vf, Po, Pl);
    k_combine<<<2048, 256, 0, stream>>>(Po, Pl, lq1, lk1, lq2, lk2, gamma, attn, nc);
    k_gemm_out<<<dim3(32, 8), 256, 0, stream>>>(attn, WoutT, out);
}

// Round 11
// 168.888 us; speedup vs baseline: 1.0728x; 1.0525x over previous
//
#include <hip/hip_runtime.h>

// ---------- types ----------
typedef __attribute__((ext_vector_type(8)))  _Float16 half8;
typedef __attribute__((ext_vector_type(4)))  _Float16 half4;
typedef __attribute__((ext_vector_type(2)))  __fp16   fp16x2;
typedef __attribute__((ext_vector_type(4)))  float    f32x4;

#define MFMA16(a,b,c) __builtin_amdgcn_mfma_f32_16x16x32_f16(a,b,c,0,0,0)

// constants
#define QSCALE       0.17677669529663687f   // 32^-0.5
#define LAMBDA_INIT  0.3555090675909693f
#define OUT_SCALE    0.6444909324090307f    // 1 - LAMBDA_INIT
#define LOG2E        1.4426950408889634f
#define MSHIFT       4.0f                   // fixed softmax shift (log2 domain)

#define EXP2(x) __builtin_amdgcn_exp2f(x)   // bare v_exp_f32 (no ocml range bloat)

__device__ __forceinline__ void gld16(const void* g, void* l) {
    __builtin_amdgcn_global_load_lds(
        (const __attribute__((address_space(1))) unsigned int*)g,
        (__attribute__((address_space(3))) unsigned int*)l, 16, 0, 0);
}

// ---------- prep: fused cvt + transposes ----------
__device__ __forceinline__ void tr64(const float* __restrict__ src,
                                     _Float16* __restrict__ dst,
                                     int srcld, int dstld, int bx, int by) {
    __shared__ float t[64][65];
    int k0 = bx * 64, n0 = by * 64;
    int c = threadIdx.x & 63, rr = threadIdx.x >> 6;
#pragma unroll
    for (int ph = 0; ph < 16; ++ph) {
        int k = ph * 4 + rr;
        t[k][c] = src[(size_t)(k0 + k) * srcld + n0 + c];
    }
    __syncthreads();
#pragma unroll
    for (int ph = 0; ph < 16; ++ph) {
        int n = ph * 4 + rr;
        dst[(size_t)(n0 + n) * dstld + k0 + c] = (_Float16)t[c][n];
    }
}

__global__ __launch_bounds__(256) void k_prep(const float* __restrict__ x,
                                              const float* __restrict__ Wq,
                                              const float* __restrict__ Wkv,
                                              const float* __restrict__ Wout,
                                              _Float16* __restrict__ xh,
                                              _Float16* __restrict__ WallT,
                                              _Float16* __restrict__ WoutT) {
    int b = blockIdx.x;
    if (b < 4096) {
        int i = (b * 256 + threadIdx.x) * 4;
        f32x4 v = *(const f32x4*)(x + i);
        half4 h;
        h[0] = (_Float16)v[0]; h[1] = (_Float16)v[1];
        h[2] = (_Float16)v[2]; h[3] = (_Float16)v[3];
        *(half4*)(xh + i) = h;
    } else if (b < 4224) {
        int idx = b - 4096;                       // Wq: [1024][512] -> WallT rows 0..511
        tr64(Wq, WallT, 512, 1024, idx & 15, idx >> 4);
    } else if (b < 4480) {
        int idx = b - 4224;                       // Wkv: [1024][1024] -> WallT rows 512..1535
        tr64(Wkv, WallT + 512 * 1024, 1024, 1024, idx & 15, idx >> 4);
    } else {
        int idx = b - 4480;                       // Wout: [512][1024] -> WoutT [1024][512]
        tr64(Wout, WoutT, 1024, 512, idx & 7, idx >> 3);
    }
}

// ---------- shared GEMM main loop: C[128x128] = A[M][K] * Bt[N][K]^T ----------
__device__ __forceinline__ void gemm_loop(const _Float16* __restrict__ A,
                                          const _Float16* __restrict__ Bt,
                                          int K, int bm, int bn,
                                          char* As, char* Bs,
                                          f32x4 (&acc)[4][4]) {
    int tid = threadIdx.x, lane = tid & 63, w = tid >> 6;
    int col16 = lane & 15, quad = lane >> 4;
    int wm = (w >> 1) << 6, wn = (w & 1) << 6;
    int r0 = tid >> 2;
    int kc = (tid & 3) << 3;
    const _Float16* ga0 = A  + (size_t)(bm + r0) * K + kc;
    const _Float16* ga1 = A  + (size_t)(bm + 64 + r0) * K + kc;
    const _Float16* gb0 = Bt + (size_t)(bn + r0) * K + kc;
    const _Float16* gb1 = Bt + (size_t)(bn + 64 + r0) * K + kc;
    char* lA = As + (w << 10);
    char* lB = Bs + (w << 10);

    for (int k0 = 0; k0 < K; k0 += 32) {
        __syncthreads();
        gld16(ga0 + k0, lA);
        gld16(ga1 + k0, lA + 4096);
        gld16(gb0 + k0, lB);
        gld16(gb1 + k0, lB + 4096);
        __syncthreads();
        half8 af[4], bf[4];
#pragma unroll
        for (int i = 0; i < 4; ++i)
            af[i] = *(const half8*)(As + ((wm + i * 16 + col16) << 6) + (quad << 4));
#pragma unroll
        for (int j = 0; j < 4; ++j)
            bf[j] = *(const half8*)(Bs + ((wn + j * 16 + col16) << 6) + (quad << 4));
#pragma unroll
        for (int i = 0; i < 4; ++i)
#pragma unroll
            for (int j = 0; j < 4; ++j)
                acc[i][j] = MFMA16(af[i], bf[j], acc[i][j]);
    }
}

// ---------- GEMM1: x @ [Wq|Wk|Wv] -> q rows + K fragments + V fragments ----------
// Kf layout: per (b*8+p, kb32): 4KB = [frag(4)][lane(64)][16B]
// Vf layout: per (b*8+p, kb32): 4KB = [t(4)][lane(64)][16B], key permutation baked in
__global__ __launch_bounds__(256) void k_gemm_qkv(const _Float16* __restrict__ xh,
                                                  const _Float16* __restrict__ WallT,
                                                  _Float16* __restrict__ qbuf,
                                                  char* __restrict__ Kf,
                                                  char* __restrict__ Vf) {
    __shared__ __align__(16) char As[8192];
    __shared__ __align__(16) char Bs[8192];
    f32x4 acc[4][4] = {};
    int bm = blockIdx.x * 128, bn = blockIdx.y * 128;
    gemm_loop(xh, WallT, 1024, bm, bn, As, Bs, acc);

    int tid = threadIdx.x, lane = tid & 63, w = tid >> 6;
    int col16 = lane & 15, quad = lane >> 4;
    int wm = (w >> 1) << 6, wn = (w & 1) << 6;

    if (bn < 512) {  // q, pre-scaled into log2-softmax domain
        const float s = QSCALE * LOG2E;
#pragma unroll
        for (int i = 0; i < 4; ++i)
#pragma unroll
            for (int j = 0; j < 4; ++j) {
                int n = bn + wn + j * 16 + col16;
                int m0 = bm + wm + i * 16 + quad * 4;
#pragma unroll
                for (int r = 0; r < 4; ++r)
                    qbuf[(size_t)(m0 + r) * 512 + n] = (_Float16)(acc[i][j][r] * s);
            }
    } else if (bn < 1024) {  // K fragments
#pragma unroll
        for (int j = 0; j < 4; ++j) {
            int n = bn + wn + j * 16 + col16 - 512;
            int pp = n >> 6, dd = n & 63, head = dd >> 5, d32 = dd & 31;
            int lbase = (d32 >> 3) << 4;
            int e2 = (d32 & 7) << 1;
            int fragb = head << 11;
#pragma unroll
            for (int i = 0; i < 4; ++i) {
                int m0 = bm + wm + i * 16 + quad * 4;
                int b = m0 >> 11, tok = m0 & 2047, kb = tok >> 5, kk = tok & 31;
                char* dst = Kf + (((size_t)((b * 8 + pp) * 64 + kb)) << 12)
                          + fragb + ((kk >> 4) << 10) + ((lbase + (kk & 15)) << 4) + e2;
#pragma unroll
                for (int r = 0; r < 4; ++r)
                    *(_Float16*)(dst + (r << 4)) = (_Float16)acc[i][j][r];
            }
        }
    } else {  // V fragments (key permutation kappa baked in)
#pragma unroll
        for (int j = 0; j < 4; ++j) {
            int n = bn + wn + j * 16 + col16 - 1024;
            int pp = n >> 6, ch = n & 63;
            int off_t = ((ch >> 4) << 10) + ((ch & 15) << 4);
#pragma unroll
            for (int i = 0; i < 4; ++i) {
                int m0 = bm + wm + i * 16 + quad * 4;
                int b = m0 >> 11, tok = m0 & 2047, kb = tok >> 5, kk = tok & 31;
                int quadv = (kk < 16) ? (kk >> 2) : ((kk - 16) >> 2);
                int e0 = (kk < 16) ? 0 : 4;
                half4 hv;
#pragma unroll
                for (int r = 0; r < 4; ++r) hv[r] = (_Float16)acc[i][j][r];
                *(half4*)(Vf + (((size_t)((b * 8 + pp) * 64 + kb)) << 12)
                          + off_t + (quadv << 8) + (e0 << 1)) = hv;
            }
        }
    }
}

// ---------- single-pass fixed-shift flash differential attention ----------
// grid nc*256; block 256 = 4 waves. Each block: 128 q-rows (2 row-groups/wave)
// x (1024/nc) keys. r6's proven 1-barrier 32KB LDS double-buffer staging; the
// 2nd q-tile doubles MFMA+exp per staged byte (in-wave ILP replaces the block
// concurrency that r7 showed doesn't help).
template <int ITERS>
__global__ __launch_bounds__(256) void k_attn(const _Float16* __restrict__ qbuf,
                                              const char* __restrict__ Kf,
                                              const char* __restrict__ Vf,
                                              _Float16* __restrict__ Po,
                                              float* __restrict__ Pl) {
    __shared__ __align__(16) char Sh[32768];   // 2 x (K 8KB + V 8KB)

    int blk = blockIdx.x;
    int qt = blk & 15, p = (blk >> 4) & 7, bb = (blk >> 7) & 1, c = blk >> 8;
    int tid = threadIdx.x, lane = tid & 63, w = tid >> 6;
    int col16 = lane & 15, quad = lane >> 4;

    int qrow = bb * 2048 + qt * 128 + w * 16 + col16;
    const _Float16* qba = qbuf + (size_t)qrow * 512 + p * 64;
    const _Float16* qbb = qba + (size_t)64 * 512;
    half8 q1a = *(const half8*)(qba + quad * 8);
    half8 q2a = *(const half8*)(qba + 32 + quad * 8);
    half8 q1b = *(const half8*)(qbb + quad * 8);
    half8 q2b = *(const half8*)(qbb + 32 + quad * 8);

    size_t choff = (size_t)c * ((size_t)ITERS << 13);
    const char* Kb = Kf + (((size_t)(bb * 8 + p)) << 18) + choff;
    const char* Vb = Vf + (((size_t)(bb * 8 + p)) << 18) + choff;
    const f32x4 minit = {-MSHIFT, -MSHIFT, -MSHIFT, -MSHIFT};  // QK acc starts at -shift
    int t16 = tid << 4;

    float l1a = 0.f, l2a = 0.f, l1b = 0.f, l2b = 0.f;
    f32x4 oa1[4] = {}, oa2[4] = {}, ob1[4] = {}, ob2[4] = {};

    auto softpack = [&](const f32x4& sa, const f32x4& sb, float& l) -> half8 {
        union { half8 v; fp16x2 h[4]; } u;
        float a0 = EXP2(sa[0]), a1 = EXP2(sa[1]);
        float a2 = EXP2(sa[2]), a3 = EXP2(sa[3]);
        float b0 = EXP2(sb[0]), b1 = EXP2(sb[1]);
        float b2 = EXP2(sb[2]), b3 = EXP2(sb[3]);
        l += ((a0 + a1) + (a2 + a3)) + ((b0 + b1) + (b2 + b3));
        u.h[0] = __builtin_amdgcn_cvt_pkrtz(a0, a1);
        u.h[1] = __builtin_amdgcn_cvt_pkrtz(a2, a3);
        u.h[2] = __builtin_amdgcn_cvt_pkrtz(b0, b1);
        u.h[3] = __builtin_amdgcn_cvt_pkrtz(b2, b3);
        return u.v;
    };

    {   // prologue: stage iter 0 into buffer 0 (r6-proven idiom)
        gld16(Kb + t16, Sh + t16);          gld16(Kb + 4096 + t16, Sh + 4096 + t16);
        gld16(Vb + t16, Sh + 8192 + t16);   gld16(Vb + 4096 + t16, Sh + 12288 + t16);
    }
    for (int it = 0; it < ITERS; ++it) {
        __syncthreads();
        const char* cur = Sh + ((it & 1) << 14);
        if (it + 1 < ITERS) {
            const char* sk = Kb + ((size_t)(it + 1) << 13);
            const char* sv = Vb + ((size_t)(it + 1) << 13);
            char* d = Sh + (((it + 1) & 1) << 14);
            gld16(sk + t16, d + t16);          gld16(sk + 4096 + t16, d + 4096 + t16);
            gld16(sv + t16, d + 8192 + t16);   gld16(sv + 4096 + t16, d + 12288 + t16);
        }
#pragma unroll
        for (int g = 0; g < 2; ++g) {
            const char* kbase = cur + (g << 12) + (lane << 4);
            const char* vbase = cur + 8192 + (g << 12) + (lane << 4);
            half8 kf0 = *(const half8*)(kbase);
            half8 kf1 = *(const half8*)(kbase + 1024);
            half8 kf2 = *(const half8*)(kbase + 2048);
            half8 kf3 = *(const half8*)(kbase + 3072);
            f32x4 sa1a = MFMA16(kf0, q1a, minit), sb1a = MFMA16(kf1, q1a, minit);
            f32x4 sa2a = MFMA16(kf2, q2a, minit), sb2a = MFMA16(kf3, q2a, minit);
            f32x4 sa1b = MFMA16(kf0, q1b, minit), sb1b = MFMA16(kf1, q1b, minit);
            f32x4 sa2b = MFMA16(kf2, q2b, minit), sb2b = MFMA16(kf3, q2b, minit);

            half8 p1a = softpack(sa1a, sb1a, l1a);
            half8 p2a = softpack(sa2a, sb2a, l2a);
            half8 p1b = softpack(sa1b, sb1b, l1b);
            half8 p2b = softpack(sa2b, sb2b, l2b);

            half8 vf0 = *(const half8*)(vbase);
            half8 vf1 = *(const half8*)(vbase + 1024);
            half8 vf2 = *(const half8*)(vbase + 2048);
            half8 vf3 = *(const half8*)(vbase + 3072);
            oa1[0] = MFMA16(p1a, vf0, oa1[0]); oa2[0] = MFMA16(p2a, vf0, oa2[0]);
            oa1[1] = MFMA16(p1a, vf1, oa1[1]); oa2[1] = MFMA16(p2a, vf1, oa2[1]);
            oa1[2] = MFMA16(p1a, vf2, oa1[2]); oa2[2] = MFMA16(p2a, vf2, oa2[2]);
            oa1[3] = MFMA16(p1a, vf3, oa1[3]); oa2[3] = MFMA16(p2a, vf3, oa2[3]);
            ob1[0] = MFMA16(p1b, vf0, ob1[0]); ob2[0] = MFMA16(p2b, vf0, ob2[0]);
            ob1[1] = MFMA16(p1b, vf1, ob1[1]); ob2[1] = MFMA16(p2b, vf1, ob2[1]);
            ob1[2] = MFMA16(p1b, vf2, ob1[2]); ob2[2] = MFMA16(p2b, vf2, ob2[2]);
            ob1[3] = MFMA16(p1b, vf3, ob1[3]); ob2[3] = MFMA16(p2b, vf3, ob2[3]);
        }
    }
    l1a += __shfl_xor(l1a, 16); l1a += __shfl_xor(l1a, 32);
    l2a += __shfl_xor(l2a, 16); l2a += __shfl_xor(l2a, 32);
    l1b += __shfl_xor(l1b, 16); l1b += __shfl_xor(l1b, 32);
    l2b += __shfl_xor(l2b, 16); l2b += __shfl_xor(l2b, 32);

    // ---- store partials (tile a, then tile b at +64 rows) ----
    int rowbase = (bb * 8 + p) * 2048 + qt * 128 + w * 16;
#pragma unroll
    for (int s = 0; s < 2; ++s) {
        int rbs = rowbase + s * 64;
        const f32x4* po1 = s ? ob1 : oa1;
        const f32x4* po2 = s ? ob2 : oa2;
        _Float16* PoC = Po + (size_t)c * 4194304 + (size_t)rbs * 128;
#pragma unroll
        for (int r = 0; r < 4; ++r) {
            int rl = quad * 4 + r;
            _Float16* dst = PoC + (size_t)rl * 128 + col16;
#pragma unroll
            for (int t = 0; t < 4; ++t) {
                dst[t * 16]      = (_Float16)po1[t][r];
                dst[64 + t * 16] = (_Float16)po2[t][r];
            }
        }
        if (quad == 0) {
            int idx = rbs + col16;
            Pl[c * 65536 + idx]         = s ? l1b : l1a;
            Pl[c * 65536 + 32768 + idx] = s ? l2b : l2a;
        }
    }
}

// ---------- combine: sum chunks, diff, RMS norm, gamma -> f16 attn ----------
// grid 2048 x 256; 16 lanes per row-instance
__global__ __launch_bounds__(256) void k_combine(const _Float16* __restrict__ Po,
                                                 const float* __restrict__ Pl,
                                                 const float* __restrict__ lq1,
                                                 const float* __restrict__ lk1,
                                                 const float* __restrict__ lq2,
                                                 const float* __restrict__ lk2,
                                                 const float* __restrict__ gamma,
                                                 _Float16* __restrict__ attnO,
                                                 int nc) {
    int gid = blockIdx.x * 256 + threadIdx.x;
    int idx = gid >> 4, j = gid & 15;

    float s1 = 0.f, s2 = 0.f;
#pragma unroll
    for (int i = 0; i < 32; ++i) { s1 += lq1[i] * lk1[i]; s2 += lq2[i] * lk2[i]; }
    float lam = __expf(s1) - __expf(s2) + LAMBDA_INIT;

    size_t rb = (size_t)idx * 128 + j * 4;
    float l1 = 0.f, l2 = 0.f;
    float o1[4] = {}, o2[4] = {};
    for (int c = 0; c < nc; ++c) {
        half4 c1 = *(const half4*)(Po + (size_t)c * 4194304 + rb);
        half4 c2 = *(const half4*)(Po + (size_t)c * 4194304 + rb + 64);
        l1 += Pl[c * 65536 + idx];
        l2 += Pl[c * 65536 + 32768 + idx];
#pragma unroll
        for (int e = 0; e < 4; ++e) { o1[e] += (float)c1[e]; o2[e] += (float)c2[e]; }
    }
    float il1 = 1.f / l1, il2 = lam / l2;
    float Of[4], ss = 0.f;
#pragma unroll
    for (int e = 0; e < 4; ++e) {
        Of[e] = o1[e] * il1 - o2[e] * il2;
        ss += Of[e] * Of[e];
    }
    ss += __shfl_xor(ss, 1, 16); ss += __shfl_xor(ss, 2, 16);
    ss += __shfl_xor(ss, 4, 16); ss += __shfl_xor(ss, 8, 16);
    float rms = sqrtf(ss * 0.015625f);
    float sc = OUT_SCALE / (rms + 1e-8f);

    int b = idx >> 14, p = (idx >> 11) & 7, t = idx & 2047;
    half4 o;
#pragma unroll
    for (int e = 0; e < 4; ++e) o[e] = (_Float16)(gamma[j * 4 + e] * Of[e] * sc);
    *(half4*)(attnO + ((size_t)(b * 2048 + t) * 512) + p * 64 + j * 4) = o;
}

// ---------- GEMM2: attn @ Wout -> fp32 out ----------
__global__ __launch_bounds__(256) void k_gemm_out(const _Float16* __restrict__ attn,
                                                  const _Float16* __restrict__ WoutT,
                                                  float* __restrict__ out) {
    __shared__ __align__(16) char As[8192];
    __shared__ __align__(16) char Bs[8192];
    f32x4 acc[4][4] = {};
    int bm = blockIdx.x * 128, bn = blockIdx.y * 128;
    gemm_loop(attn, WoutT, 512, bm, bn, As, Bs, acc);

    int tid = threadIdx.x, lane = tid & 63, w = tid >> 6;
    int col16 = lane & 15, quad = lane >> 4;
    int wm = (w >> 1) << 6, wn = (w & 1) << 6;
#pragma unroll
    for (int i = 0; i < 4; ++i)
#pragma unroll
        for (int j = 0; j < 4; ++j) {
            int n = bn + wn + j * 16 + col16;
            int m0 = bm + wm + i * 16 + quad * 4;
#pragma unroll
            for (int r = 0; r < 4; ++r)
                out[(size_t)(m0 + r) * 1024 + n] = acc[i][j][r];
        }
}

// ---------- launch ----------
extern "C" void kernel_launch(void* const* d_in, const int* in_sizes, int n_in,
                              void* d_out, int out_size, void* d_ws, size_t ws_size,
                              hipStream_t stream) {
    const float* x     = (const float*)d_in[0];
    const float* Wq    = (const float*)d_in[1];
    const float* Wkv   = (const float*)d_in[2];
    const float* Wout  = (const float*)d_in[3];
    const float* lq1   = (const float*)d_in[4];
    const float* lk1   = (const float*)d_in[5];
    const float* lq2   = (const float*)d_in[6];
    const float* lk2   = (const float*)d_in[7];
    const float* gamma = (const float*)d_in[8];
    float* out = (float*)d_out;

    char* ws = (char*)d_ws;
    // Layout: [xh 8M][WallT 3M | Pl 1M overlay][WoutT 1M][qbuf 4M][Kf 4M][Vf 4M]
    //         [attn 4M][Po nc*8M @28M]. Peak (nc=2): 44 MB; ws measured 256 MiB.
    _Float16* xh    = (_Float16*)(ws);                 // 4096*1024  (8 MB)
    _Float16* WallT = (_Float16*)(ws + 8388608);       // 1536*1024  (3 MB)
    float*    Pl    = (float*)(ws + 8388608);          // nc*2*32768 (<=512 KB, overlays WallT)
    _Float16* WoutT = (_Float16*)(ws + 11534336);      // 1024*512   (1 MB)
    _Float16* qbuf  = (_Float16*)(ws + 12582912);      // 4096*512   (4 MB)
    char*     Kf    = (char*)(ws + 16777216);          // 16*64*4096 (4 MB)
    char*     Vf    = (char*)(ws + 20971520);          // 16*64*4096 (4 MB)
    _Float16* attn  = (_Float16*)(ws + 25165824);      // 4096*512   (4 MB)
    _Float16* Po    = (_Float16*)(ws + 29360128);      // nc*4194304 elems (nc*8 MB)

    int nc = (ws_size >= 46137344u) ? 2 : 1;           // fall back if ws too small

    k_prep<<<4608, 256, 0, stream>>>(x, Wq, Wkv, Wout, xh, WallT, WoutT);
    k_gemm_qkv<<<dim3(32, 12), 256, 0, stream>>>(xh, WallT, qbuf, Kf, Vf);
    if (nc == 2)
        k_attn<16><<<512, 256, 0, stream>>>(qbuf, Kf, Vf, Po, Pl);
    else
        k_attn<32><<<256, 256, 0, stream>>>(qbuf, Kf, Vf, Po, Pl);
    k_combine<<<2048, 256, 0, stream>>>(Po, Pl, lq1, lk1, lq2, lk2, gamma, attn, nc);
    k_gemm_out<<<dim3(32, 8), 256, 0, stream>>>(attn, WoutT, out);
}